// Round 1
// baseline (288.866 us; speedup 1.0000x reference)
//
#include <hip/hip_runtime.h>
#include <math.h>

#define BATCH 8
#define T 1024
#define NH 8
#define NROW 8192
#define NEG_INF (-INFINITY)
#define SENT (-1.0e30f)

typedef __attribute__((ext_vector_type(8))) short short8;   // 8 bf16 (4 VGPRs)
typedef __attribute__((ext_vector_type(4))) float f32x4;

// fp32 -> bf16 (RNE)
__device__ __forceinline__ ushort f2bf(float x) {
  uint u = __float_as_uint(x);
  return (ushort)((u + 0x7FFFu + ((u >> 16) & 1u)) >> 16);
}
__device__ __forceinline__ uint pack2(float a, float b) {
  return (uint)f2bf(a) | ((uint)f2bf(b) << 16);
}
// async global->LDS, 16B per lane; LDS dest = wave-uniform base + lane*16
__device__ __forceinline__ void gl_lds16(const ushort* g, ushort* l) {
  __builtin_amdgcn_global_load_lds(
      (const __attribute__((address_space(1))) unsigned int*)g,
      (__attribute__((address_space(3))) unsigned int*)l, 16, 0, 0);
}

// ---------------------------------------------------------------- n_valid
__global__ __launch_bounds__(256) void k_nvalid(const int* __restrict__ tokens,
                                                int* __restrict__ nv) {
  int b = blockIdx.x, t = threadIdx.x;
  int cnt = 0;
  for (int i = t; i < T; i += 256) cnt += (tokens[b * T + i] != 0) ? 1 : 0;
  __shared__ int s[256];
  s[t] = cnt;
  __syncthreads();
  for (int st = 128; st > 0; st >>= 1) {
    if (t < st) s[t] += s[t + st];
    __syncthreads();
  }
  if (t == 0) nv[b] = s[0];
}

// ---------------------------------------------------------------- W -> bf16 concat
__global__ __launch_bounds__(256) void k_prep_w(const float* __restrict__ Wq,
                                                const float* __restrict__ Wk,
                                                ushort* __restrict__ Wbf) {
  const int gid = blockIdx.x * 256 + threadIdx.x;  // 0..131071
  const int e0 = gid * 8;
  const int n = e0 >> 10, k = e0 & 1023;
  const float* src = (n < 512) ? (Wq + (size_t)n * 1024 + k)
                               : (Wk + (size_t)(n - 512) * 1024 + k);
  float4 a = *(const float4*)src;
  float4 b = *(const float4*)(src + 4);
  uint4 o;
  o.x = pack2(a.x, a.y); o.y = pack2(a.z, a.w);
  o.z = pack2(b.x, b.y); o.w = pack2(b.z, b.w);
  *(uint4*)(Wbf + (size_t)n * 1024 + k) = o;
}

// ---------------------------------------------------------------- f = concat(feat,pos) -> bf16
__global__ __launch_bounds__(256) void k_prep_f(const float* __restrict__ feat,
                                                const float* __restrict__ pos,
                                                ushort* __restrict__ fbf) {
  const int gid = blockIdx.x * 256 + threadIdx.x;  // 0..1048575
  const int e0 = gid * 8;
  const int r = e0 >> 10, k = e0 & 1023;
  const float* src = (k < 512) ? (feat + (size_t)r * 512 + k)
                               : (pos + (size_t)r * 512 + (k - 512));
  float4 a = *(const float4*)src;
  float4 b = *(const float4*)(src + 4);
  uint4 o;
  o.x = pack2(a.x, a.y); o.y = pack2(a.z, a.w);
  o.z = pack2(b.x, b.y); o.w = pack2(b.z, b.w);
  *(uint4*)(fbf + (size_t)r * 1024 + k) = o;
}

// ---------------------------------------------------------------- fused q/k GEMM (m97 structure)
// C[8192 x 1024] = fbf @ Wbf^T + bias. 128x128 tile, BK=64, global_load_lds staging,
// XCD-chunked swizzle: each XCD owns 8 m-tiles x all n (A 2MB + B 2MB = its 4MB L2).
__global__ __launch_bounds__(256) void k_gemm(
    const ushort* __restrict__ fbf, const ushort* __restrict__ Wbf,
    const float* __restrict__ bq, const float* __restrict__ bk,
    ushort* __restrict__ qbuf, ushort* __restrict__ kbuf) {
  const int g = blockIdx.x + 8 * blockIdx.y;   // dispatch-linear id; xcd ~ g%8
  const int wid = (g & 7) * 64 + (g >> 3);     // bijective (512 = 8*64)
  const int n0 = (wid & 7) * 128;
  const int m0 = (wid >> 3) * 128;
  const int tid = threadIdx.x;
  const int w = tid >> 6, l = tid & 63;
  const int lo = l & 15, quad = l >> 4;
  const int wm0 = (w >> 1) * 64, wn0 = (w & 1) * 64;

  __shared__ ushort As[128 * 64];  // linear: row-major [128][64], gl_lds writes in order
  __shared__ ushort Bs[128 * 64];

  f32x4 acc[4][4];
#pragma unroll
  for (int i = 0; i < 4; ++i)
#pragma unroll
    for (int j = 0; j < 4; ++j) acc[i][j] = (f32x4){0.f, 0.f, 0.f, 0.f};

  const int c8 = (tid & 7) * 8;  // low 3 bits invariant under +256
  const int r0 = tid >> 3;       // + u*32
  ushort* lA = As + (size_t)w * 512;  // + u*2048 : element base (u*256 + w*64)*8
  ushort* lB = Bs + (size_t)w * 512;

  for (int k0 = 0; k0 < 1024; k0 += 64) {
    __syncthreads();  // previous compute done before overwrite
#pragma unroll
    for (int u = 0; u < 4; ++u) {
      gl_lds16(fbf + (size_t)(m0 + u * 32 + r0) * 1024 + k0 + c8, lA + u * 2048);
      gl_lds16(Wbf + (size_t)(n0 + u * 32 + r0) * 1024 + k0 + c8, lB + u * 2048);
    }
    __syncthreads();  // compiler emits vmcnt(0) drain here
#pragma unroll
    for (int kk = 0; kk < 2; ++kk) {
      short8 af[4], bfr[4];
#pragma unroll
      for (int mi = 0; mi < 4; ++mi)
        af[mi] = *(const short8*)(As + (size_t)(wm0 + mi * 16 + lo) * 64 + kk * 32 + quad * 8);
#pragma unroll
      for (int ni = 0; ni < 4; ++ni)
        bfr[ni] = *(const short8*)(Bs + (size_t)(wn0 + ni * 16 + lo) * 64 + kk * 32 + quad * 8);
#pragma unroll
      for (int mi = 0; mi < 4; ++mi)
#pragma unroll
        for (int ni = 0; ni < 4; ++ni)
          acc[mi][ni] = __builtin_amdgcn_mfma_f32_16x16x32_bf16(af[mi], bfr[ni], acc[mi][ni], 0, 0, 0);
    }
  }

  // epilogue: bias + bf16 store
  float bv[4];
#pragma unroll
  for (int ni = 0; ni < 4; ++ni) {
    const int gn = n0 + wn0 + ni * 16 + lo;
    bv[ni] = (gn < 512) ? bq[gn] : bk[gn - 512];
  }
#pragma unroll
  for (int mi = 0; mi < 4; ++mi)
#pragma unroll
    for (int ni = 0; ni < 4; ++ni) {
      const int gn = n0 + wn0 + ni * 16 + lo;
      ushort* dst = (gn < 512) ? (qbuf + gn) : (kbuf + gn - 512);
#pragma unroll
      for (int r = 0; r < 4; ++r) {
        const int m = m0 + wm0 + mi * 16 + quad * 4 + r;
        dst[(size_t)m * 512] = f2bf(acc[mi][ni][r] + bv[ni]);
      }
    }
}

// ---------------------------------------------------------------- gates: Wg in LDS, 4 rows/block
__global__ __launch_bounds__(256) void k_gates(
    const float* __restrict__ feat, const float* __restrict__ pos,
    const float* __restrict__ Wg, const float* __restrict__ bg,
    float* __restrict__ gout) {
  __shared__ __align__(16) float Ws[8192];  // 8 x 1024 fp32 = 32 KB
  const int tid = threadIdx.x;
#pragma unroll
  for (int u = 0; u < 8; ++u)
    ((float4*)Ws)[u * 256 + tid] = ((const float4*)Wg)[u * 256 + tid];
  __syncthreads();

  const int w = tid >> 6, l = tid & 63;
  const int row = blockIdx.x * 4 + w;
  const int c0 = l * 16;
  const float* src = (c0 < 512) ? (feat + (size_t)row * 512 + c0)
                                : (pos + (size_t)row * 512 + (c0 - 512));
  float4 f0 = *(const float4*)(src + 0);
  float4 f1 = *(const float4*)(src + 4);
  float4 f2 = *(const float4*)(src + 8);
  float4 f3 = *(const float4*)(src + 12);
  float s[8];
#pragma unroll
  for (int h = 0; h < 8; ++h) {
    const float* wg = Ws + h * 1024 + c0;
    float4 w0 = *(const float4*)(wg + 0);
    float4 w1 = *(const float4*)(wg + 4);
    float4 w2 = *(const float4*)(wg + 8);
    float4 w3 = *(const float4*)(wg + 12);
    s[h] = f0.x * w0.x + f0.y * w0.y + f0.z * w0.z + f0.w * w0.w
         + f1.x * w1.x + f1.y * w1.y + f1.z * w1.z + f1.w * w1.w
         + f2.x * w2.x + f2.y * w2.y + f2.z * w2.z + f2.w * w2.w
         + f3.x * w3.x + f3.y * w3.y + f3.z * w3.z + f3.w * w3.w;
  }
#pragma unroll
  for (int m = 1; m < 64; m <<= 1)
#pragma unroll
    for (int h = 0; h < 8; ++h) s[h] += __shfl_xor(s[h], m, 64);
  if (l == 0) {
    float lg[8], mx = -1e30f;
#pragma unroll
    for (int h = 0; h < 8; ++h) { lg[h] = s[h] + bg[h]; mx = fmaxf(mx, lg[h]); }
    float sum = 0.f;
#pragma unroll
    for (int h = 0; h < 8; ++h) sum += __expf(lg[h] - mx);
    const float lse = mx + __logf(sum);
#pragma unroll
    for (int h = 0; h < 8; ++h) gout[(size_t)row * 8 + h] = lg[h] - lse;
  }
}

// ---------------------------------------------------------------- pass1: no-LDS register flash
// Wt[h][row] = g[row][h] - log(sum_j exp(s/8))   (NEG_INF if empty band)
__global__ __launch_bounds__(256) void k_pass1(
    const ushort* __restrict__ q, const ushort* __restrict__ kv,
    const float* __restrict__ g, const int* __restrict__ nvp,
    float* __restrict__ Wt) {
  const int it = blockIdx.x, h = blockIdx.y, b = blockIdx.z;
  const int nv = nvp[b];
  const int i0 = it * 64;
  const int tid = threadIdx.x;
  const int w = tid >> 6, l = tid & 63;
  const int lo = l & 15, quad = l >> 4;

  // A-fragment direct from global (rows i0+w*16+lo, 64B contiguous per row across quads)
  const ushort* qp = q + (size_t)(b * T + i0 + w * 16 + lo) * 512 + h * 64 + quad * 8;
  const short8 a0 = *(const short8*)qp;
  const short8 a1 = *(const short8*)(qp + 32);

  float lsum[4] = {0.f, 0.f, 0.f, 0.f};
  const ushort* kb = kv + (size_t)(b * T + lo) * 512 + h * 64 + quad * 8;
  for (int jt = it; jt * 64 < nv; ++jt) {
    const int j0 = jt * 64;
#pragma unroll
    for (int ni = 0; ni < 4; ++ni) {
      const ushort* kp = kb + (size_t)(j0 + ni * 16) * 512;
      const short8 b0 = *(const short8*)kp;
      const short8 b1 = *(const short8*)(kp + 32);
      f32x4 acc = (f32x4){0.f, 0.f, 0.f, 0.f};
      acc = __builtin_amdgcn_mfma_f32_16x16x32_bf16(a0, b0, acc, 0, 0, 0);
      acc = __builtin_amdgcn_mfma_f32_16x16x32_bf16(a1, b1, acc, 0, 0, 0);
      const int j = j0 + ni * 16 + lo;
#pragma unroll
      for (int r = 0; r < 4; ++r) {
        const int i = i0 + w * 16 + quad * 4 + r;
        if (j > i && j < nv) lsum[r] += __expf(acc[r] * 0.125f);
      }
    }
  }
#pragma unroll
  for (int m = 1; m < 16; m <<= 1)
#pragma unroll
    for (int r = 0; r < 4; ++r) lsum[r] += __shfl_xor(lsum[r], m, 64);
  if (lo == 0) {
#pragma unroll
    for (int r = 0; r < 4; ++r) {
      const size_t row = (size_t)(b * T) + i0 + w * 16 + quad * 4 + r;
      Wt[(size_t)h * NROW + row] =
          (lsum[r] > 0.f) ? (g[row * 8 + h] - __logf(lsum[r])) : NEG_INF;
    }
  }
}

// ---------------------------------------------------------------- pass2: no-LDS register flash
// out[b,i,j] = log( sum_h exp(s/8 + Wt[h][i]) ), no barriers, no LDS.
__global__ __launch_bounds__(256) void k_pass2(
    const ushort* __restrict__ q, const ushort* __restrict__ kv,
    const float* __restrict__ Wt, const int* __restrict__ nvp,
    float* __restrict__ out) {
  const int jt = blockIdx.x, it = blockIdx.y, b = blockIdx.z;
  const int nv = nvp[b];
  const int i0 = it * 64, j0 = jt * 64;
  const int tid = threadIdx.x;

  if (jt < it || j0 >= nv) {
    const int r0 = tid >> 4, c0 = (tid & 15) * 4;
    float4 v; v.x = v.y = v.z = v.w = SENT;
#pragma unroll
    for (int u = 0; u < 4; ++u)
      *(float4*)(out + ((size_t)(b * T + i0 + r0 + u * 16)) * T + j0 + c0) = v;
    return;
  }

  const int w = tid >> 6, l = tid & 63;
  const int lo = l & 15, quad = l >> 4;
  const int irow = i0 + w * 16 + quad * 4;

  const ushort* qb = q + (size_t)(b * T + i0 + w * 16 + lo) * 512 + quad * 8;
  const ushort* kb = kv + (size_t)(b * T + j0 + lo) * 512 + quad * 8;

  float se[4][4];  // [ni][r]
#pragma unroll
  for (int a = 0; a < 4; ++a)
#pragma unroll
    for (int c = 0; c < 4; ++c) se[a][c] = 0.f;

  for (int h = 0; h < 8; ++h) {
    const short8 a0 = *(const short8*)(qb + h * 64);
    const short8 a1 = *(const short8*)(qb + h * 64 + 32);
    const float4 wv = *(const float4*)(Wt + (size_t)h * NROW + b * T + irow);
#pragma unroll
    for (int ni = 0; ni < 4; ++ni) {
      const ushort* kp = kb + (size_t)(ni * 16) * 512 + h * 64;
      const short8 b0 = *(const short8*)kp;
      const short8 b1 = *(const short8*)(kp + 32);
      f32x4 acc = (f32x4){0.f, 0.f, 0.f, 0.f};
      acc = __builtin_amdgcn_mfma_f32_16x16x32_bf16(a0, b0, acc, 0, 0, 0);
      acc = __builtin_amdgcn_mfma_f32_16x16x32_bf16(a1, b1, acc, 0, 0, 0);
      se[ni][0] += __expf(acc[0] * 0.125f + wv.x);
      se[ni][1] += __expf(acc[1] * 0.125f + wv.y);
      se[ni][2] += __expf(acc[2] * 0.125f + wv.z);
      se[ni][3] += __expf(acc[3] * 0.125f + wv.w);
    }
  }

#pragma unroll
  for (int ni = 0; ni < 4; ++ni) {
    const int j = j0 + ni * 16 + lo;
#pragma unroll
    for (int r = 0; r < 4; ++r) {
      const int i = irow + r;
      out[((size_t)(b * T + i)) * T + j] =
          (j > i && j < nv) ? fmaxf(__logf(se[ni][r]), SENT) : SENT;
    }
  }
}

// ---------------------------------------------------------------- launch
extern "C" void kernel_launch(void* const* d_in, const int* in_sizes, int n_in,
                              void* d_out, int out_size, void* d_ws, size_t ws_size,
                              hipStream_t stream) {
  (void)in_sizes; (void)n_in; (void)out_size; (void)ws_size;
  const float* feat = (const float*)d_in[0];
  const float* pos  = (const float*)d_in[1];
  const int* tokens = (const int*)d_in[2];
  const float* Wq = (const float*)d_in[3];
  const float* bq = (const float*)d_in[4];
  const float* Wk = (const float*)d_in[5];
  const float* bk = (const float*)d_in[6];
  const float* Wg = (const float*)d_in[7];
  const float* bg = (const float*)d_in[8];
  float* out = (float*)d_out;

  // workspace: qbuf 8.4M | kbuf 8.4M | Wbf 2M | gbuf 256K | Wt 256K | nv
  ushort* qbuf = (ushort*)d_ws;
  ushort* kbuf = qbuf + (size_t)NROW * 512;
  ushort* Wbf  = kbuf + (size_t)NROW * 512;
  float*  gbuf = (float*)(Wbf + (size_t)1024 * 1024);
  float*  Wt   = gbuf + (size_t)NROW * NH;
  int*    nv   = (int*)(Wt + (size_t)NH * NROW);

  // fbf (bf16 concat of feat,pos; 16.8 MB) lives in d_out (33.5 MB) —
  // consumed by k_gemm, fully overwritten later by k_pass2.
  ushort* fbf = (ushort*)d_out;

  k_nvalid<<<dim3(BATCH), dim3(256), 0, stream>>>(tokens, nv);
  k_prep_w<<<dim3(512), dim3(256), 0, stream>>>(Wq, Wk, Wbf);
  k_prep_f<<<dim3(4096), dim3(256), 0, stream>>>(feat, pos, fbf);
  k_gemm<<<dim3(8, 64), dim3(256), 0, stream>>>(fbf, Wbf, bq, bk, qbuf, kbuf);
  k_gates<<<dim3(2048), dim3(256), 0, stream>>>(feat, pos, Wg, bg, gbuf);
  k_pass1<<<dim3(16, NH, BATCH), dim3(256), 0, stream>>>(qbuf, kbuf, gbuf, nv, Wt);
  k_pass2<<<dim3(16, 16, BATCH), dim3(256), 0, stream>>>(qbuf, kbuf, Wt, nv, out);
}

// Round 2
// 196.445 us; speedup vs baseline: 1.4705x; 1.4705x over previous
//
#include <hip/hip_runtime.h>
#include <math.h>

#define BATCH 8
#define T 1024
#define NH 8
#define NROW 8192
#define NEG_INF (-INFINITY)
#define SENT (-1.0e30f)

typedef __attribute__((ext_vector_type(8))) short short8;   // 8 bf16 (4 VGPRs)
typedef __attribute__((ext_vector_type(4))) float f32x4;

// fp32 -> bf16 (RNE)
__device__ __forceinline__ ushort f2bf(float x) {
  uint u = __float_as_uint(x);
  return (ushort)((u + 0x7FFFu + ((u >> 16) & 1u)) >> 16);
}
__device__ __forceinline__ uint pack2(float a, float b) {
  return (uint)f2bf(a) | ((uint)f2bf(b) << 16);
}
// async global->LDS, 16B per lane; LDS dest = wave-uniform base + lane*16
__device__ __forceinline__ void gl_lds16(const ushort* g, ushort* l) {
  __builtin_amdgcn_global_load_lds(
      (const __attribute__((address_space(1))) unsigned int*)g,
      (__attribute__((address_space(3))) unsigned int*)l, 16, 0, 0);
}

// ---------------------------------------------------------------- n_valid
__global__ __launch_bounds__(256) void k_nvalid(const int* __restrict__ tokens,
                                                int* __restrict__ nv) {
  int b = blockIdx.x, t = threadIdx.x;
  int cnt = 0;
  for (int i = t; i < T; i += 256) cnt += (tokens[b * T + i] != 0) ? 1 : 0;
  __shared__ int s[256];
  s[t] = cnt;
  __syncthreads();
  for (int st = 128; st > 0; st >>= 1) {
    if (t < st) s[t] += s[t + st];
    __syncthreads();
  }
  if (t == 0) nv[b] = s[0];
}

// ---------------------------------------------------------------- W -> bf16 concat
__global__ __launch_bounds__(256) void k_prep_w(const float* __restrict__ Wq,
                                                const float* __restrict__ Wk,
                                                ushort* __restrict__ Wbf) {
  const int gid = blockIdx.x * 256 + threadIdx.x;  // 0..131071
  const int e0 = gid * 8;
  const int n = e0 >> 10, k = e0 & 1023;
  const float* src = (n < 512) ? (Wq + (size_t)n * 1024 + k)
                               : (Wk + (size_t)(n - 512) * 1024 + k);
  float4 a = *(const float4*)src;
  float4 b = *(const float4*)(src + 4);
  uint4 o;
  o.x = pack2(a.x, a.y); o.y = pack2(a.z, a.w);
  o.z = pack2(b.x, b.y); o.w = pack2(b.z, b.w);
  *(uint4*)(Wbf + (size_t)n * 1024 + k) = o;
}

// ---------------------------------------------------------------- fused prep_f + gates
// One streaming pass over feat/pos: bf16-pack into fbf AND gate log-softmax.
// 8 rows/block (2 per wave); Wg staged once per block in LDS.
__global__ __launch_bounds__(256) void k_prep_fg(
    const float* __restrict__ feat, const float* __restrict__ pos,
    const float* __restrict__ Wg, const float* __restrict__ bg,
    ushort* __restrict__ fbf, float* __restrict__ gout) {
  __shared__ __align__(16) float Ws[8192];  // 8 x 1024 fp32 = 32 KB
  const int tid = threadIdx.x;
#pragma unroll
  for (int u = 0; u < 8; ++u)
    ((float4*)Ws)[u * 256 + tid] = ((const float4*)Wg)[u * 256 + tid];
  __syncthreads();

  const int w = tid >> 6, l = tid & 63;
  const int c0 = l * 16;
  const int row0 = blockIdx.x * 8 + w * 2;

  float4 f[2][4];
#pragma unroll
  for (int r = 0; r < 2; ++r) {
    const int row = row0 + r;
    const float* src = (c0 < 512) ? (feat + (size_t)row * 512 + c0)
                                  : (pos + (size_t)row * 512 + (c0 - 512));
#pragma unroll
    for (int q4 = 0; q4 < 4; ++q4) f[r][q4] = *(const float4*)(src + q4 * 4);
    uint4 o0, o1;
    o0.x = pack2(f[r][0].x, f[r][0].y); o0.y = pack2(f[r][0].z, f[r][0].w);
    o0.z = pack2(f[r][1].x, f[r][1].y); o0.w = pack2(f[r][1].z, f[r][1].w);
    o1.x = pack2(f[r][2].x, f[r][2].y); o1.y = pack2(f[r][2].z, f[r][2].w);
    o1.z = pack2(f[r][3].x, f[r][3].y); o1.w = pack2(f[r][3].z, f[r][3].w);
    *(uint4*)(fbf + (size_t)row * 1024 + c0) = o0;
    *(uint4*)(fbf + (size_t)row * 1024 + c0 + 8) = o1;
  }

  float s[2][8];
#pragma unroll
  for (int h = 0; h < 8; ++h) {
    const float* wg = Ws + h * 1024 + c0;
    float4 w0 = *(const float4*)(wg + 0);
    float4 w1 = *(const float4*)(wg + 4);
    float4 w2 = *(const float4*)(wg + 8);
    float4 w3 = *(const float4*)(wg + 12);
#pragma unroll
    for (int r = 0; r < 2; ++r)
      s[r][h] = f[r][0].x * w0.x + f[r][0].y * w0.y + f[r][0].z * w0.z + f[r][0].w * w0.w
              + f[r][1].x * w1.x + f[r][1].y * w1.y + f[r][1].z * w1.z + f[r][1].w * w1.w
              + f[r][2].x * w2.x + f[r][2].y * w2.y + f[r][2].z * w2.z + f[r][2].w * w2.w
              + f[r][3].x * w3.x + f[r][3].y * w3.y + f[r][3].z * w3.z + f[r][3].w * w3.w;
  }
#pragma unroll
  for (int m = 1; m < 64; m <<= 1)
#pragma unroll
    for (int r = 0; r < 2; ++r)
#pragma unroll
      for (int h = 0; h < 8; ++h) s[r][h] += __shfl_xor(s[r][h], m, 64);
  if (l == 0) {
#pragma unroll
    for (int r = 0; r < 2; ++r) {
      float lg[8], mx = -1e30f;
#pragma unroll
      for (int h = 0; h < 8; ++h) { lg[h] = s[r][h] + bg[h]; mx = fmaxf(mx, lg[h]); }
      float sum = 0.f;
#pragma unroll
      for (int h = 0; h < 8; ++h) sum += __expf(lg[h] - mx);
      const float lse = mx + __logf(sum);
#pragma unroll
      for (int h = 0; h < 8; ++h) gout[(size_t)(row0 + r) * 8 + h] = lg[h] - lse;
    }
  }
}

// ---------------------------------------------------------------- fused q/k GEMM (unchanged)
__global__ __launch_bounds__(256) void k_gemm(
    const ushort* __restrict__ fbf, const ushort* __restrict__ Wbf,
    const float* __restrict__ bq, const float* __restrict__ bk,
    ushort* __restrict__ qbuf, ushort* __restrict__ kbuf) {
  const int g = blockIdx.x + 8 * blockIdx.y;   // dispatch-linear id; xcd ~ g%8
  const int wid = (g & 7) * 64 + (g >> 3);     // bijective (512 = 8*64)
  const int n0 = (wid & 7) * 128;
  const int m0 = (wid >> 3) * 128;
  const int tid = threadIdx.x;
  const int w = tid >> 6, l = tid & 63;
  const int lo = l & 15, quad = l >> 4;
  const int wm0 = (w >> 1) * 64, wn0 = (w & 1) * 64;

  __shared__ ushort As[128 * 64];  // linear: row-major [128][64], gl_lds writes in order
  __shared__ ushort Bs[128 * 64];

  f32x4 acc[4][4];
#pragma unroll
  for (int i = 0; i < 4; ++i)
#pragma unroll
    for (int j = 0; j < 4; ++j) acc[i][j] = (f32x4){0.f, 0.f, 0.f, 0.f};

  const int c8 = (tid & 7) * 8;
  const int r0 = tid >> 3;
  ushort* lA = As + (size_t)w * 512;
  ushort* lB = Bs + (size_t)w * 512;

  for (int k0 = 0; k0 < 1024; k0 += 64) {
    __syncthreads();
#pragma unroll
    for (int u = 0; u < 4; ++u) {
      gl_lds16(fbf + (size_t)(m0 + u * 32 + r0) * 1024 + k0 + c8, lA + u * 2048);
      gl_lds16(Wbf + (size_t)(n0 + u * 32 + r0) * 1024 + k0 + c8, lB + u * 2048);
    }
    __syncthreads();
#pragma unroll
    for (int kk = 0; kk < 2; ++kk) {
      short8 af[4], bfr[4];
#pragma unroll
      for (int mi = 0; mi < 4; ++mi)
        af[mi] = *(const short8*)(As + (size_t)(wm0 + mi * 16 + lo) * 64 + kk * 32 + quad * 8);
#pragma unroll
      for (int ni = 0; ni < 4; ++ni)
        bfr[ni] = *(const short8*)(Bs + (size_t)(wn0 + ni * 16 + lo) * 64 + kk * 32 + quad * 8);
#pragma unroll
      for (int mi = 0; mi < 4; ++mi)
#pragma unroll
        for (int ni = 0; ni < 4; ++ni)
          acc[mi][ni] = __builtin_amdgcn_mfma_f32_16x16x32_bf16(af[mi], bfr[ni], acc[mi][ni], 0, 0, 0);
    }
  }

  float bv[4];
#pragma unroll
  for (int ni = 0; ni < 4; ++ni) {
    const int gn = n0 + wn0 + ni * 16 + lo;
    bv[ni] = (gn < 512) ? bq[gn] : bk[gn - 512];
  }
#pragma unroll
  for (int mi = 0; mi < 4; ++mi)
#pragma unroll
    for (int ni = 0; ni < 4; ++ni) {
      const int gn = n0 + wn0 + ni * 16 + lo;
      ushort* dst = (gn < 512) ? (qbuf + gn) : (kbuf + gn - 512);
#pragma unroll
      for (int r = 0; r < 4; ++r) {
        const int m = m0 + wm0 + mi * 16 + quad * 4 + r;
        dst[(size_t)m * 512] = f2bf(acc[mi][ni][r] + bv[ni]);
      }
    }
}

// ---------------------------------------------------------------- pass1: K double-buffered LDS
// Wt[h][row] = g[row][h] - log(sum_j exp(s/8)); 2-phase prefetch, 1 barrier/tile.
// LDS layout: per-head K tile [64 rows][8 chunks of 16B], chunk XOR-swizzled by row&7
// (source pre-swizzled so global_load_lds stays linear; read applies same XOR).
__global__ __launch_bounds__(256) void k_pass1(
    const ushort* __restrict__ q, const ushort* __restrict__ kv,
    const float* __restrict__ g, const int* __restrict__ nvp,
    float* __restrict__ Wt) {
  const int it = blockIdx.x, h = blockIdx.y, b = blockIdx.z;
  const int nv = nvp[b];
  const int i0 = it * 64;
  const int tid = threadIdx.x;
  const int w = tid >> 6, l = tid & 63;
  const int lo = l & 15, quad = l >> 4;

  __shared__ ushort Ks[2][64 * 64];  // 2 x 8 KB

  // Q fragment direct from global (reused across all K tiles)
  const ushort* qp = q + (size_t)(b * T + i0 + w * 16 + lo) * 512 + h * 64 + quad * 8;
  const short8 a0 = *(const short8*)qp;
  const short8 a1 = *(const short8*)(qp + 32);

  float lsum[4] = {0.f, 0.f, 0.f, 0.f};
  const int ntile = ((nv + 63) >> 6) - it;  // tiles jt = it .. it+ntile-1

  if (ntile > 0) {
    // stage(buf, jt): 512 chunks; lane chunk s = u*256+tid, row=s>>3, c=s&7;
    // global source chunk = c ^ (row&7)  (involution; read undoes it)
    auto stage = [&](int buf, int jt) {
#pragma unroll
      for (int u = 0; u < 2; ++u) {
        const int s = u * 256 + tid;
        const int row = s >> 3, c = s & 7;
        gl_lds16(kv + (size_t)(b * T + jt * 64 + row) * 512 + h * 64 + ((c ^ (row & 7)) * 8),
                 Ks[buf] + (size_t)(u * 256 + w * 64) * 8);
      }
    };
    stage(0, it);
    __syncthreads();
    for (int s = 0; s < ntile; ++s) {
      if (s + 1 < ntile) stage((s + 1) & 1, it + s + 1);
      const ushort* kbase = Ks[s & 1];
      const int j0 = (it + s) * 64;
#pragma unroll
      for (int ni = 0; ni < 4; ++ni) {
        const int rw = ni * 16 + lo;
        const short8 b0 = *(const short8*)(kbase + (size_t)rw * 64 + ((quad ^ (rw & 7)) * 8));
        const short8 b1 = *(const short8*)(kbase + (size_t)rw * 64 + (((4 + quad) ^ (rw & 7)) * 8));
        f32x4 acc = (f32x4){0.f, 0.f, 0.f, 0.f};
        acc = __builtin_amdgcn_mfma_f32_16x16x32_bf16(a0, b0, acc, 0, 0, 0);
        acc = __builtin_amdgcn_mfma_f32_16x16x32_bf16(a1, b1, acc, 0, 0, 0);
        const int j = j0 + ni * 16 + lo;
#pragma unroll
        for (int r = 0; r < 4; ++r) {
          const int i = i0 + w * 16 + quad * 4 + r;
          if (j > i && j < nv) lsum[r] += __expf(acc[r] * 0.125f);
        }
      }
      __syncthreads();  // prefetch complete (vmcnt drain) + buffer reuse safe
    }
  }

#pragma unroll
  for (int m = 1; m < 16; m <<= 1)
#pragma unroll
    for (int r = 0; r < 4; ++r) lsum[r] += __shfl_xor(lsum[r], m, 64);
  if (lo == 0) {
#pragma unroll
    for (int r = 0; r < 4; ++r) {
      const size_t row = (size_t)(b * T) + i0 + w * 16 + quad * 4 + r;
      Wt[(size_t)h * NROW + row] =
          (lsum[r] > 0.f) ? (g[row * 8 + h] - __logf(lsum[r])) : NEG_INF;
    }
  }
}

// ---------------------------------------------------------------- pass2: K staged once (all heads)
// Q fragments in registers (64 VGPR), K tile 64x512 bf16 = 64 KB LDS, ONE barrier.
// LDS linear [64 rows][64 chunks]; source chunk pre-swizzled c^=(row&7); read undoes.
__global__ __launch_bounds__(256) void k_pass2(
    const ushort* __restrict__ q, const ushort* __restrict__ kv,
    const float* __restrict__ Wt, const int* __restrict__ nvp,
    float* __restrict__ out) {
  const int jt = blockIdx.x, it = blockIdx.y, b = blockIdx.z;
  const int nv = nvp[b];
  const int i0 = it * 64, j0 = jt * 64;
  const int tid = threadIdx.x;

  if (jt < it || j0 >= nv) {
    const int r0 = tid >> 4, c0 = (tid & 15) * 4;
    float4 v; v.x = v.y = v.z = v.w = SENT;
#pragma unroll
    for (int u = 0; u < 4; ++u)
      *(float4*)(out + ((size_t)(b * T + i0 + r0 + u * 16)) * T + j0 + c0) = v;
    return;
  }

  const int w = tid >> 6, l = tid & 63;
  const int lo = l & 15, quad = l >> 4;
  const int irow = i0 + w * 16 + quad * 4;

  __shared__ ushort Ks[64 * 512];  // 64 KB, linear rows of 1 KB

  // stage K: iteration u stages one full row (64 chunks) per wave; row = u*4+w
#pragma unroll
  for (int u = 0; u < 16; ++u) {
    const int row = u * 4 + w;
    gl_lds16(kv + (size_t)(b * T + j0 + row) * 512 + ((l ^ (row & 7)) * 8),
             Ks + (size_t)(u * 256 + w * 64) * 8);
  }

  // Q fragments, all 8 heads (loads overlap the staging)
  const ushort* qb = q + (size_t)(b * T + i0 + w * 16 + lo) * 512 + quad * 8;
  short8 qa0[8], qa1[8];
#pragma unroll
  for (int h = 0; h < 8; ++h) {
    qa0[h] = *(const short8*)(qb + h * 64);
    qa1[h] = *(const short8*)(qb + h * 64 + 32);
  }

  float se[4][4];  // [ni][r]
#pragma unroll
  for (int a = 0; a < 4; ++a)
#pragma unroll
    for (int c = 0; c < 4; ++c) se[a][c] = 0.f;

  __syncthreads();  // staging (and Q loads) complete

#pragma unroll
  for (int h = 0; h < 8; ++h) {
    const float4 wv = *(const float4*)(Wt + (size_t)h * NROW + b * T + irow);
#pragma unroll
    for (int ni = 0; ni < 4; ++ni) {
      const int rw = ni * 16 + lo;
      const int cs0 = (h * 8 + quad) ^ (rw & 7);
      const int cs1 = (h * 8 + 4 + quad) ^ (rw & 7);
      const short8 b0 = *(const short8*)(Ks + (size_t)rw * 512 + cs0 * 8);
      const short8 b1 = *(const short8*)(Ks + (size_t)rw * 512 + cs1 * 8);
      f32x4 acc = (f32x4){0.f, 0.f, 0.f, 0.f};
      acc = __builtin_amdgcn_mfma_f32_16x16x32_bf16(qa0[h], b0, acc, 0, 0, 0);
      acc = __builtin_amdgcn_mfma_f32_16x16x32_bf16(qa1[h], b1, acc, 0, 0, 0);
      se[ni][0] += __expf(acc[0] * 0.125f + wv.x);
      se[ni][1] += __expf(acc[1] * 0.125f + wv.y);
      se[ni][2] += __expf(acc[2] * 0.125f + wv.z);
      se[ni][3] += __expf(acc[3] * 0.125f + wv.w);
    }
  }

#pragma unroll
  for (int ni = 0; ni < 4; ++ni) {
    const int j = j0 + ni * 16 + lo;
#pragma unroll
    for (int r = 0; r < 4; ++r) {
      const int i = irow + r;
      out[((size_t)(b * T + i)) * T + j] =
          (j > i && j < nv) ? fmaxf(__logf(se[ni][r]), SENT) : SENT;
    }
  }
}

// ---------------------------------------------------------------- launch
extern "C" void kernel_launch(void* const* d_in, const int* in_sizes, int n_in,
                              void* d_out, int out_size, void* d_ws, size_t ws_size,
                              hipStream_t stream) {
  (void)in_sizes; (void)n_in; (void)out_size; (void)ws_size;
  const float* feat = (const float*)d_in[0];
  const float* pos  = (const float*)d_in[1];
  const int* tokens = (const int*)d_in[2];
  const float* Wq = (const float*)d_in[3];
  const float* bq = (const float*)d_in[4];
  const float* Wk = (const float*)d_in[5];
  const float* bk = (const float*)d_in[6];
  const float* Wg = (const float*)d_in[7];
  const float* bg = (const float*)d_in[8];
  float* out = (float*)d_out;

  // workspace: qbuf 8.4M | kbuf 8.4M | Wbf 2M | gbuf 256K | Wt 256K | nv
  ushort* qbuf = (ushort*)d_ws;
  ushort* kbuf = qbuf + (size_t)NROW * 512;
  ushort* Wbf  = kbuf + (size_t)NROW * 512;
  float*  gbuf = (float*)(Wbf + (size_t)1024 * 1024);
  float*  Wt   = gbuf + (size_t)NROW * NH;
  int*    nv   = (int*)(Wt + (size_t)NH * NROW);

  // fbf (bf16 concat of feat,pos; 16.8 MB) lives in d_out (33.5 MB) —
  // consumed by k_gemm, fully overwritten later by k_pass2.
  ushort* fbf = (ushort*)d_out;

  k_nvalid<<<dim3(BATCH), dim3(256), 0, stream>>>(tokens, nv);
  k_prep_w<<<dim3(512), dim3(256), 0, stream>>>(Wq, Wk, Wbf);
  k_prep_fg<<<dim3(1024), dim3(256), 0, stream>>>(feat, pos, Wg, bg, fbf, gbuf);
  k_gemm<<<dim3(8, 64), dim3(256), 0, stream>>>(fbf, Wbf, bq, bk, qbuf, kbuf);
  k_pass1<<<dim3(16, NH, BATCH), dim3(256), 0, stream>>>(qbuf, kbuf, gbuf, nv, Wt);
  k_pass2<<<dim3(16, 16, BATCH), dim3(256), 0, stream>>>(qbuf, kbuf, Wt, nv, out);
}

// Round 3
// 189.784 us; speedup vs baseline: 1.5221x; 1.0351x over previous
//
#include <hip/hip_runtime.h>
#include <math.h>

#define BATCH 8
#define T 1024
#define NH 8
#define NROW 8192
#define NEG_INF (-INFINITY)
#define SENT (-1.0e30f)
#define SC 0.180336880f      // 0.125 * log2(e)
#define LOG2E 1.442695041f

typedef __attribute__((ext_vector_type(8))) short short8;   // 8 bf16 (4 VGPRs)
typedef __attribute__((ext_vector_type(4))) float f32x4;

// fp32 -> bf16 (RNE)
__device__ __forceinline__ ushort f2bf(float x) {
  uint u = __float_as_uint(x);
  return (ushort)((u + 0x7FFFu + ((u >> 16) & 1u)) >> 16);
}
__device__ __forceinline__ uint pack2(float a, float b) {
  return (uint)f2bf(a) | ((uint)f2bf(b) << 16);
}
// async global->LDS, 16B per lane; LDS dest = wave-uniform base + lane*16
__device__ __forceinline__ void gl_lds16(const ushort* g, ushort* l) {
  __builtin_amdgcn_global_load_lds(
      (const __attribute__((address_space(1))) unsigned int*)g,
      (__attribute__((address_space(3))) unsigned int*)l, 16, 0, 0);
}

// ---------------------------------------------------------------- n_valid
__global__ __launch_bounds__(256) void k_nvalid(const int* __restrict__ tokens,
                                                int* __restrict__ nv) {
  int b = blockIdx.x, t = threadIdx.x;
  int cnt = 0;
  for (int i = t; i < T; i += 256) cnt += (tokens[b * T + i] != 0) ? 1 : 0;
  __shared__ int s[256];
  s[t] = cnt;
  __syncthreads();
  for (int st = 128; st > 0; st >>= 1) {
    if (t < st) s[t] += s[t + st];
    __syncthreads();
  }
  if (t == 0) nv[b] = s[0];
}

// ---------------------------------------------------------------- W -> bf16 concat
__global__ __launch_bounds__(256) void k_prep_w(const float* __restrict__ Wq,
                                                const float* __restrict__ Wk,
                                                ushort* __restrict__ Wbf) {
  const int gid = blockIdx.x * 256 + threadIdx.x;  // 0..131071
  const int e0 = gid * 8;
  const int n = e0 >> 10, k = e0 & 1023;
  const float* src = (n < 512) ? (Wq + (size_t)n * 1024 + k)
                               : (Wk + (size_t)(n - 512) * 1024 + k);
  float4 a = *(const float4*)src;
  float4 b = *(const float4*)(src + 4);
  uint4 o;
  o.x = pack2(a.x, a.y); o.y = pack2(a.z, a.w);
  o.z = pack2(b.x, b.y); o.w = pack2(b.z, b.w);
  *(uint4*)(Wbf + (size_t)n * 1024 + k) = o;
}

// ---------------------------------------------------------------- fused prep_f + gates
__global__ __launch_bounds__(256) void k_prep_fg(
    const float* __restrict__ feat, const float* __restrict__ pos,
    const float* __restrict__ Wg, const float* __restrict__ bg,
    ushort* __restrict__ fbf, float* __restrict__ gout) {
  __shared__ __align__(16) float Ws[8192];  // 8 x 1024 fp32 = 32 KB
  const int tid = threadIdx.x;
#pragma unroll
  for (int u = 0; u < 8; ++u)
    ((float4*)Ws)[u * 256 + tid] = ((const float4*)Wg)[u * 256 + tid];
  __syncthreads();

  const int w = tid >> 6, l = tid & 63;
  const int c0 = l * 16;
  const int row0 = blockIdx.x * 8 + w * 2;

  float4 f[2][4];
#pragma unroll
  for (int r = 0; r < 2; ++r) {
    const int row = row0 + r;
    const float* src = (c0 < 512) ? (feat + (size_t)row * 512 + c0)
                                  : (pos + (size_t)row * 512 + (c0 - 512));
#pragma unroll
    for (int q4 = 0; q4 < 4; ++q4) f[r][q4] = *(const float4*)(src + q4 * 4);
    uint4 o0, o1;
    o0.x = pack2(f[r][0].x, f[r][0].y); o0.y = pack2(f[r][0].z, f[r][0].w);
    o0.z = pack2(f[r][1].x, f[r][1].y); o0.w = pack2(f[r][1].z, f[r][1].w);
    o1.x = pack2(f[r][2].x, f[r][2].y); o1.y = pack2(f[r][2].z, f[r][2].w);
    o1.z = pack2(f[r][3].x, f[r][3].y); o1.w = pack2(f[r][3].z, f[r][3].w);
    *(uint4*)(fbf + (size_t)row * 1024 + c0) = o0;
    *(uint4*)(fbf + (size_t)row * 1024 + c0 + 8) = o1;
  }

  float s[2][8];
#pragma unroll
  for (int h = 0; h < 8; ++h) {
    const float* wg = Ws + h * 1024 + c0;
    float4 w0 = *(const float4*)(wg + 0);
    float4 w1 = *(const float4*)(wg + 4);
    float4 w2 = *(const float4*)(wg + 8);
    float4 w3 = *(const float4*)(wg + 12);
#pragma unroll
    for (int r = 0; r < 2; ++r)
      s[r][h] = f[r][0].x * w0.x + f[r][0].y * w0.y + f[r][0].z * w0.z + f[r][0].w * w0.w
              + f[r][1].x * w1.x + f[r][1].y * w1.y + f[r][1].z * w1.z + f[r][1].w * w1.w
              + f[r][2].x * w2.x + f[r][2].y * w2.y + f[r][2].z * w2.z + f[r][2].w * w2.w
              + f[r][3].x * w3.x + f[r][3].y * w3.y + f[r][3].z * w3.z + f[r][3].w * w3.w;
  }
#pragma unroll
  for (int m = 1; m < 64; m <<= 1)
#pragma unroll
    for (int r = 0; r < 2; ++r)
#pragma unroll
      for (int h = 0; h < 8; ++h) s[r][h] += __shfl_xor(s[r][h], m, 64);
  if (l == 0) {
#pragma unroll
    for (int r = 0; r < 2; ++r) {
      float lg[8], mx = -1e30f;
#pragma unroll
      for (int h = 0; h < 8; ++h) { lg[h] = s[r][h] + bg[h]; mx = fmaxf(mx, lg[h]); }
      float sum = 0.f;
#pragma unroll
      for (int h = 0; h < 8; ++h) sum += __expf(lg[h] - mx);
      const float lse = mx + __logf(sum);
#pragma unroll
      for (int h = 0; h < 8; ++h) gout[(size_t)(row0 + r) * 8 + h] = lg[h] - lse;
    }
  }
}

// ---------------------------------------------------------------- fused q/k GEMM
// Swapped-operand MFMA: lane holds row m (= lo), 4 consecutive cols n -> ushort4 stores.
__global__ __launch_bounds__(256) void k_gemm(
    const ushort* __restrict__ fbf, const ushort* __restrict__ Wbf,
    const float* __restrict__ bq, const float* __restrict__ bk,
    ushort* __restrict__ qbuf, ushort* __restrict__ kbuf) {
  const int g = blockIdx.x + 8 * blockIdx.y;   // dispatch-linear id; xcd ~ g%8
  const int wid = (g & 7) * 64 + (g >> 3);     // bijective (512 = 8*64)
  const int n0 = (wid & 7) * 128;
  const int m0 = (wid >> 3) * 128;
  const int tid = threadIdx.x;
  const int w = tid >> 6, l = tid & 63;
  const int lo = l & 15, quad = l >> 4;
  const int wm0 = (w >> 1) * 64, wn0 = (w & 1) * 64;

  __shared__ ushort As[128 * 64];  // linear row-major [128][64]
  __shared__ ushort Bs[128 * 64];

  f32x4 acc[4][4];
#pragma unroll
  for (int i = 0; i < 4; ++i)
#pragma unroll
    for (int j = 0; j < 4; ++j) acc[i][j] = (f32x4){0.f, 0.f, 0.f, 0.f};

  const int c8 = (tid & 7) * 8;
  const int r0 = tid >> 3;
  ushort* lA = As + (size_t)w * 512;
  ushort* lB = Bs + (size_t)w * 512;

  for (int k0 = 0; k0 < 1024; k0 += 64) {
    __syncthreads();
#pragma unroll
    for (int u = 0; u < 4; ++u) {
      gl_lds16(fbf + (size_t)(m0 + u * 32 + r0) * 1024 + k0 + c8, lA + u * 2048);
      gl_lds16(Wbf + (size_t)(n0 + u * 32 + r0) * 1024 + k0 + c8, lB + u * 2048);
    }
    __syncthreads();
#pragma unroll
    for (int kk = 0; kk < 2; ++kk) {
      short8 af[4], bfr[4];
#pragma unroll
      for (int mi = 0; mi < 4; ++mi)
        af[mi] = *(const short8*)(As + (size_t)(wm0 + mi * 16 + lo) * 64 + kk * 32 + quad * 8);
#pragma unroll
      for (int ni = 0; ni < 4; ++ni)
        bfr[ni] = *(const short8*)(Bs + (size_t)(wn0 + ni * 16 + lo) * 64 + kk * 32 + quad * 8);
#pragma unroll
      for (int mi = 0; mi < 4; ++mi)
#pragma unroll
        for (int ni = 0; ni < 4; ++ni)  // swapped: rows(quad,reg)=n, cols(lo)=m
          acc[mi][ni] = __builtin_amdgcn_mfma_f32_16x16x32_bf16(bfr[ni], af[mi], acc[mi][ni], 0, 0, 0);
    }
  }

  // epilogue: lane owns row m = ...+lo, 4 consecutive n per (ni)
  float4 bias4[4];
#pragma unroll
  for (int ni = 0; ni < 4; ++ni) {
    const int gn = n0 + wn0 + ni * 16 + quad * 4;
    bias4[ni] = *(const float4*)((gn < 512) ? (bq + gn) : (bk + gn - 512));
  }
#pragma unroll
  for (int mi = 0; mi < 4; ++mi) {
    const int m = m0 + wm0 + mi * 16 + lo;
#pragma unroll
    for (int ni = 0; ni < 4; ++ni) {
      const int gn = n0 + wn0 + ni * 16 + quad * 4;
      ushort* dst = (gn < 512) ? (qbuf + (size_t)m * 512 + gn)
                               : (kbuf + (size_t)m * 512 + gn - 512);
      ushort4 o;
      o.x = f2bf(acc[mi][ni][0] + bias4[ni].x);
      o.y = f2bf(acc[mi][ni][1] + bias4[ni].y);
      o.z = f2bf(acc[mi][ni][2] + bias4[ni].z);
      o.w = f2bf(acc[mi][ni][3] + bias4[ni].w);
      *(ushort4*)dst = o;
    }
  }
}

// ---------------------------------------------------------------- pass1: K dbuf LDS, swapped MFMA
// lane owns row i (= lo), j varies in-reg -> scalar lsum, maskless interior tiles.
__global__ __launch_bounds__(256) void k_pass1(
    const ushort* __restrict__ q, const ushort* __restrict__ kv,
    const float* __restrict__ g, const int* __restrict__ nvp,
    float* __restrict__ Wt) {
  const int it = blockIdx.x, h = blockIdx.y, b = blockIdx.z;
  const int nv = nvp[b];
  const int i0 = it * 64;
  const int tid = threadIdx.x;
  const int w = tid >> 6, l = tid & 63;
  const int lo = l & 15, quad = l >> 4;

  __shared__ ushort Ks[2][64 * 64];  // 2 x 8 KB

  const int i = i0 + w * 16 + lo;
  const ushort* qp = q + (size_t)(b * T + i) * 512 + h * 64 + quad * 8;
  const short8 a0 = *(const short8*)qp;
  const short8 a1 = *(const short8*)(qp + 32);

  float lsum = 0.f;
  const int ntile = ((nv + 63) >> 6) - it;

  if (ntile > 0) {
    auto stage = [&](int buf, int jt) {
#pragma unroll
      for (int u = 0; u < 2; ++u) {
        const int s = u * 256 + tid;
        const int row = s >> 3, c = s & 7;
        gl_lds16(kv + (size_t)(b * T + jt * 64 + row) * 512 + h * 64 + ((c ^ (row & 7)) * 8),
                 Ks[buf] + (size_t)(u * 256 + w * 64) * 8);
      }
    };
    stage(0, it);
    __syncthreads();
    for (int s = 0; s < ntile; ++s) {
      if (s + 1 < ntile) stage((s + 1) & 1, it + s + 1);
      const ushort* kbase = Ks[s & 1];
      const int j0 = (it + s) * 64;
      const bool diag = (s == 0);
      const bool masked = diag | (j0 + 64 > nv);
#pragma unroll
      for (int ni = 0; ni < 4; ++ni) {
        if (diag && ni < w) continue;  // entire sub-tile below diagonal (wave-uniform)
        const int rw = ni * 16 + lo;
        const short8 b0 = *(const short8*)(kbase + (size_t)rw * 64 + ((quad ^ (rw & 7)) * 8));
        const short8 b1 = *(const short8*)(kbase + (size_t)rw * 64 + (((4 + quad) ^ (rw & 7)) * 8));
        f32x4 acc = (f32x4){0.f, 0.f, 0.f, 0.f};
        acc = __builtin_amdgcn_mfma_f32_16x16x32_bf16(b0, a0, acc, 0, 0, 0);
        acc = __builtin_amdgcn_mfma_f32_16x16x32_bf16(b1, a1, acc, 0, 0, 0);
        if (!masked) {
#pragma unroll
          for (int r = 0; r < 4; ++r) lsum += __builtin_amdgcn_exp2f(acc[r] * SC);
        } else {
          const int jb = j0 + ni * 16 + quad * 4;
#pragma unroll
          for (int r = 0; r < 4; ++r) {
            const int j = jb + r;
            if (j > i && j < nv) lsum += __builtin_amdgcn_exp2f(acc[r] * SC);
          }
        }
      }
      __syncthreads();  // prefetch complete + buffer reuse safe
    }
  }

  lsum += __shfl_xor(lsum, 16, 64);
  lsum += __shfl_xor(lsum, 32, 64);
  if (quad == 0) {
    const size_t row = (size_t)(b * T) + i;
    // log2 -> ln: lsum is sum of 2^(s*SC) = sum of exp(s/8)
    Wt[(size_t)h * NROW + row] =
        (lsum > 0.f) ? (g[row * 8 + h] - __logf(lsum)) : NEG_INF;
  }
}

// ---------------------------------------------------------------- pass2: K staged once, swapped MFMA
// lane owns row i (= lo); per (ni) 4 consecutive j -> float4 stores; Wt scalar per lane.
__global__ __launch_bounds__(256) void k_pass2(
    const ushort* __restrict__ q, const ushort* __restrict__ kv,
    const float* __restrict__ Wt, const int* __restrict__ nvp,
    float* __restrict__ out) {
  const int jt = blockIdx.x, it = blockIdx.y, b = blockIdx.z;
  const int nv = nvp[b];
  const int i0 = it * 64, j0 = jt * 64;
  const int tid = threadIdx.x;

  if (jt < it || j0 >= nv) {
    const int r0 = tid >> 4, c0 = (tid & 15) * 4;
    float4 v; v.x = v.y = v.z = v.w = SENT;
#pragma unroll
    for (int u = 0; u < 4; ++u)
      *(float4*)(out + ((size_t)(b * T + i0 + r0 + u * 16)) * T + j0 + c0) = v;
    return;
  }

  const int w = tid >> 6, l = tid & 63;
  const int lo = l & 15, quad = l >> 4;
  const int i = i0 + w * 16 + lo;

  __shared__ ushort Ks[64 * 512];  // 64 KB, linear rows of 1 KB

#pragma unroll
  for (int u = 0; u < 16; ++u) {
    const int row = u * 4 + w;
    gl_lds16(kv + (size_t)(b * T + j0 + row) * 512 + ((l ^ (row & 7)) * 8),
             Ks + (size_t)(u * 256 + w * 64) * 8);
  }

  // Q fragments + per-row weights, all 8 heads (overlap the staging)
  const ushort* qb = q + (size_t)(b * T + i) * 512 + quad * 8;
  short8 qa0[8], qa1[8];
  float wl[8];
#pragma unroll
  for (int h = 0; h < 8; ++h) {
    qa0[h] = *(const short8*)(qb + h * 64);
    qa1[h] = *(const short8*)(qb + h * 64 + 32);
    wl[h] = Wt[(size_t)h * NROW + b * T + i] * LOG2E;  // -inf stays -inf
  }

  float se[4][4];  // [ni][r], r = j offset
#pragma unroll
  for (int a = 0; a < 4; ++a)
#pragma unroll
    for (int c = 0; c < 4; ++c) se[a][c] = 0.f;

  __syncthreads();  // staging complete

#pragma unroll
  for (int h = 0; h < 8; ++h) {
#pragma unroll
    for (int ni = 0; ni < 4; ++ni) {
      const int rw = ni * 16 + lo;
      const int cs0 = (h * 8 + quad) ^ (rw & 7);
      const int cs1 = (h * 8 + 4 + quad) ^ (rw & 7);
      const short8 b0 = *(const short8*)(Ks + (size_t)rw * 512 + cs0 * 8);
      const short8 b1 = *(const short8*)(Ks + (size_t)rw * 512 + cs1 * 8);
      f32x4 acc = (f32x4){0.f, 0.f, 0.f, 0.f};
      acc = __builtin_amdgcn_mfma_f32_16x16x32_bf16(b0, qa0[h], acc, 0, 0, 0);
      acc = __builtin_amdgcn_mfma_f32_16x16x32_bf16(b1, qa1[h], acc, 0, 0, 0);
#pragma unroll
      for (int r = 0; r < 4; ++r)
        se[ni][r] += __builtin_amdgcn_exp2f(acc[r] * SC + wl[h]);
    }
  }

  const size_t orow = ((size_t)(b * T + i)) * T;
#pragma unroll
  for (int ni = 0; ni < 4; ++ni) {
    const int jb = j0 + ni * 16 + quad * 4;
    float4 v;
    v.x = (jb + 0 > i && jb + 0 < nv) ? fmaxf(__logf(se[ni][0]), SENT) : SENT;
    v.y = (jb + 1 > i && jb + 1 < nv) ? fmaxf(__logf(se[ni][1]), SENT) : SENT;
    v.z = (jb + 2 > i && jb + 2 < nv) ? fmaxf(__logf(se[ni][2]), SENT) : SENT;
    v.w = (jb + 3 > i && jb + 3 < nv) ? fmaxf(__logf(se[ni][3]), SENT) : SENT;
    *(float4*)(out + orow + jb) = v;
  }
}

// ---------------------------------------------------------------- launch
extern "C" void kernel_launch(void* const* d_in, const int* in_sizes, int n_in,
                              void* d_out, int out_size, void* d_ws, size_t ws_size,
                              hipStream_t stream) {
  (void)in_sizes; (void)n_in; (void)out_size; (void)ws_size;
  const float* feat = (const float*)d_in[0];
  const float* pos  = (const float*)d_in[1];
  const int* tokens = (const int*)d_in[2];
  const float* Wq = (const float*)d_in[3];
  const float* bq = (const float*)d_in[4];
  const float* Wk = (const float*)d_in[5];
  const float* bk = (const float*)d_in[6];
  const float* Wg = (const float*)d_in[7];
  const float* bg = (const float*)d_in[8];
  float* out = (float*)d_out;

  // workspace: qbuf 8.4M | kbuf 8.4M | Wbf 2M | gbuf 256K | Wt 256K | nv
  ushort* qbuf = (ushort*)d_ws;
  ushort* kbuf = qbuf + (size_t)NROW * 512;
  ushort* Wbf  = kbuf + (size_t)NROW * 512;
  float*  gbuf = (float*)(Wbf + (size_t)1024 * 1024);
  float*  Wt   = gbuf + (size_t)NROW * NH;
  int*    nv   = (int*)(Wt + (size_t)NH * NROW);

  // fbf (bf16 concat of feat,pos) lives in d_out; consumed by k_gemm,
  // fully overwritten later by k_pass2.
  ushort* fbf = (ushort*)d_out;

  k_nvalid<<<dim3(BATCH), dim3(256), 0, stream>>>(tokens, nv);
  k_prep_w<<<dim3(512), dim3(256), 0, stream>>>(Wq, Wk, Wbf);
  k_prep_fg<<<dim3(1024), dim3(256), 0, stream>>>(feat, pos, Wg, bg, fbf, gbuf);
  k_gemm<<<dim3(8, 64), dim3(256), 0, stream>>>(fbf, Wbf, bq, bk, qbuf, kbuf);
  k_pass1<<<dim3(16, NH, BATCH), dim3(256), 0, stream>>>(qbuf, kbuf, gbuf, nv, Wt);
  k_pass2<<<dim3(16, 16, BATCH), dim3(256), 0, stream>>>(qbuf, kbuf, Wt, nv, out);
}